// Round 5
// baseline (668.850 us; speedup 1.0000x reference)
//
#include <hip/hip_runtime.h>

// ---------------- problem constants ----------------
#define NS   4096      // sequence length
#define NBAT 2         // batch
#define NH   4         // heads
#define DKH  256       // head qk dim
#define DVH  512       // head v dim
#define DM   1024      // d_model
#define VD   2048      // value dim
#define CH   64        // chunk
#define NCH  64        // num chunks
#define MROW (NBAT * NS)   // 8192

typedef unsigned short u16;
typedef unsigned int   u32;

using bf16x8 = __attribute__((ext_vector_type(8))) short;
using bf16x4 = __attribute__((ext_vector_type(4))) short;
using f32x4  = __attribute__((ext_vector_type(4))) float;

__device__ __forceinline__ float bf2f(u16 a) {
  return __uint_as_float(((u32)a) << 16);
}
__device__ __forceinline__ u16 f2bf(float f) {
  u32 u = __float_as_uint(f);
  u32 r = (u + 0x7fffu + ((u >> 16) & 1u)) >> 16;   // RNE
  return (u16)r;
}
__device__ __forceinline__ void unpack2(u32 v, float& lo, float& hi) {
  lo = __uint_as_float(v << 16);
  hi = __uint_as_float(v & 0xffff0000u);
}
__device__ __forceinline__ void unpack8(uint4 v, float* f) {
  unpack2(v.x, f[0], f[1]); unpack2(v.y, f[2], f[3]);
  unpack2(v.z, f[4], f[5]); unpack2(v.w, f[6], f[7]);
}

__device__ __forceinline__ void gl_lds16(const u16* g, u16* l) {
  __builtin_amdgcn_global_load_lds(
      (const __attribute__((address_space(1))) void*)g,
      (__attribute__((address_space(3))) void*)l,
      16, 0, 0);
}

__device__ __forceinline__ f32x4 mfma32(bf16x8 a, bf16x8 b, f32x4 c) {
  return __builtin_amdgcn_mfma_f32_16x16x32_bf16(a, b, c, 0, 0, 0);
}

// K=16 bf16 MFMA: B-operand layout (4 k per quad) matches C-layout rows.
__device__ __forceinline__ f32x4 mfma16(bf16x4 a, bf16x4 b, f32x4 c) {
#if __has_builtin(__builtin_amdgcn_mfma_f32_16x16x16bf16_1k)
  return __builtin_amdgcn_mfma_f32_16x16x16bf16_1k(a, b, c, 0, 0, 0);
#else
  asm("v_mfma_f32_16x16x16_bf16 %0, %1, %2, %0" : "+v"(c) : "v"(a), "v"(b));
  return c;
#endif
}

// scale a B-fragment's 8 bf16 by per-element k factors
__device__ __forceinline__ bf16x8 scale8(bf16x8 v, const float* ckv) {
  u32* w = (u32*)&v;
  bf16x8 out;
  u32* ow = (u32*)&out;
#pragma unroll
  for (int p = 0; p < 4; p++) {
    float lo, hi; unpack2(w[p], lo, hi);
    ow[p] = (u32)f2bf(lo * ckv[2 * p]) | ((u32)f2bf(hi * ckv[2 * p + 1]) << 16);
  }
  return out;
}

__device__ __forceinline__ bf16x4 pack4(f32x4 v) {
  bf16x4 o;
  o[0] = (short)f2bf(v[0]); o[1] = (short)f2bf(v[1]);
  o[2] = (short)f2bf(v[2]); o[3] = (short)f2bf(v[3]);
  return o;
}

// ---------------- f32 -> bf16 convert ----------------
__global__ __launch_bounds__(256) void cvt_bf16(const float* __restrict__ X,
                                                u16* __restrict__ Y) {
  size_t t = (size_t)blockIdx.x * 256 + threadIdx.x;
  float4 v = *(const float4*)(X + t * 4);
  ushort4 o;
  o.x = f2bf(v.x); o.y = f2bf(v.y); o.z = f2bf(v.z); o.w = f2bf(v.w);
  *(ushort4*)(Y + t * 4) = o;
}

// ---------------- f32 KxN -> bf16 NxK transpose-convert ----------------
__global__ __launch_bounds__(256) void transpose_bf16(const float* __restrict__ W,
                                                      u16* __restrict__ Wt,
                                                      int K, int N) {
  __shared__ float tile[64][65];
  const int n0 = blockIdx.x * 64, k0 = blockIdx.y * 64;
  const int t = threadIdx.x;
  const int r = t >> 4, c = (t & 15) << 2;
#pragma unroll
  for (int it = 0; it < 4; it++) {
    float4 v = *(const float4*)(W + (size_t)(k0 + r + it * 16) * N + n0 + c);
    tile[r + it * 16][c + 0] = v.x; tile[r + it * 16][c + 1] = v.y;
    tile[r + it * 16][c + 2] = v.z; tile[r + it * 16][c + 3] = v.w;
  }
  __syncthreads();
#pragma unroll
  for (int it = 0; it < 4; it++) {
    const int nr = r + it * 16;
    ushort4 o;
    o.x = f2bf(tile[c + 0][nr]); o.y = f2bf(tile[c + 1][nr]);
    o.z = f2bf(tile[c + 2][nr]); o.w = f2bf(tile[c + 3][nr]);
    *(ushort4*)(Wt + (size_t)(n0 + nr) * K + k0 + c) = o;
  }
}

// ---------------- MFMA GEMM: C = A @ Bt^T ----------------
// OMODE: 0 = f32 row-major, 1 = bf16 row-major, 2 = bf16 transposed (ldC = M)
template<int OMODE>
__global__ __launch_bounds__(256) void gemm_mfma(const u16* __restrict__ A,
                                                 const u16* __restrict__ Bt,
                                                 void* __restrict__ C,
                                                 int M, int N, int K) {
  __shared__ u16 sA[128 * 64];
  __shared__ u16 sB[128 * 64];
  const int tid = threadIdx.x;
  const int wave = tid >> 6, lane = tid & 63;
  const int wm = (wave >> 1) << 6;
  const int wn = (wave & 1) << 6;
  const int row0 = blockIdx.y << 7, col0 = blockIdx.x << 7;

  const int srow = tid >> 3;
  const int sk   = (tid & 7) << 3;

  const u16* aRow = A + (size_t)(row0 + srow) * K + sk;
  const u16* bRow = Bt + (size_t)(col0 + srow) * K + sk;
  u16* sAp = sA + tid * 8;
  u16* sBp = sB + tid * 8;

  f32x4 acc[4][4] = {};

  const int fm = lane & 15;
  const int fk = (lane >> 4) << 3;
  const u16* sAf = sA + (wm + fm) * 64 + fk;
  const u16* sBf = sB + (wn + fm) * 64 + fk;

  for (int k0 = 0; k0 < K; k0 += 64) {
#pragma unroll
    for (int it = 0; it < 4; it++) {
      gl_lds16(aRow + (size_t)(it * 32) * K + k0, sAp + it * 2048);
      gl_lds16(bRow + (size_t)(it * 32) * K + k0, sBp + it * 2048);
    }
    __syncthreads();
#pragma unroll
    for (int kk = 0; kk < 64; kk += 32) {
      bf16x8 af[4], bfr[4];
#pragma unroll
      for (int mt = 0; mt < 4; mt++) af[mt] = *(const bf16x8*)(sAf + mt * 1024 + kk);
#pragma unroll
      for (int nt = 0; nt < 4; nt++) bfr[nt] = *(const bf16x8*)(sBf + nt * 1024 + kk);
#pragma unroll
      for (int mt = 0; mt < 4; mt++)
#pragma unroll
        for (int nt = 0; nt < 4; nt++)
          acc[mt][nt] = mfma32(af[mt], bfr[nt], acc[mt][nt]);
    }
    __syncthreads();
  }

  const int er = lane >> 4;
  const int ec = lane & 15;
#pragma unroll
  for (int mt = 0; mt < 4; mt++) {
#pragma unroll
    for (int nt = 0; nt < 4; nt++) {
      if constexpr (OMODE == 2) {
        ushort4 o;
        o.x = f2bf(acc[mt][nt][0]); o.y = f2bf(acc[mt][nt][1]);
        o.z = f2bf(acc[mt][nt][2]); o.w = f2bf(acc[mt][nt][3]);
        u16* dst = (u16*)C + (size_t)(col0 + wn + nt * 16 + ec) * M +
                   row0 + wm + mt * 16 + er * 4;
        *(ushort4*)dst = o;
      } else {
#pragma unroll
        for (int r = 0; r < 4; r++) {
          const size_t row = (size_t)row0 + wm + mt * 16 + er * 4 + r;
          const size_t col = (size_t)col0 + wn + nt * 16 + ec;
          if constexpr (OMODE == 1) ((u16*)C)[row * N + col] = f2bf(acc[mt][nt][r]);
          else                      ((float*)C)[row * N + col] = acc[mt][nt][r];
        }
      }
    }
  }
}

// ---------------- RoPE (in-place on bf16 Q,K) + q scale ----------------
__global__ __launch_bounds__(256) void rope_kernel(u16* __restrict__ Q, u16* __restrict__ K) {
  size_t t = (size_t)blockIdx.x * 256 + threadIdx.x;   // B*N*NH*128 total
  int j = (int)(t & 127);
  int h = (int)((t >> 7) & 3);
  size_t bn = t >> 9;
  int n = (int)(bn & (NS - 1));
  float ang = (float)n * exp2f(-(float)j * (13.2877123795494f / 128.0f));
  float s, c;
  sincosf(ang, &s, &c);
  size_t base = bn * DM + (size_t)h * DKH + j;
  const float sc = 0.0625f;   // HEAD_QK^-0.5
  float q1 = bf2f(Q[base]), q2 = bf2f(Q[base + 128]);
  Q[base]       = f2bf((q1 * c - q2 * s) * sc);
  Q[base + 128] = f2bf((q2 * c + q1 * s) * sc);
  float k1 = bf2f(K[base]), k2 = bf2f(K[base + 128]);
  K[base]       = f2bf(k1 * c - k2 * s);
  K[base + 128] = f2bf(k2 * c + k1 * s);
}

// ---------------- K -> K^T (per head): KT[b,h,d,n] ----------------
__global__ __launch_bounds__(256) void transpose_k(const u16* __restrict__ Kb,
                                                   u16* __restrict__ KT) {
  __shared__ u16 tile[64][68];
  const int wg = blockIdx.x;
  const int dt = wg & 3, nt = (wg >> 2) & 63, h = (wg >> 8) & 3, b = wg >> 10;
  const int tid = threadIdx.x;
  const int r = tid >> 2, cb = (tid & 3) << 4;
  const u16* src = Kb + (size_t)(b * NS + nt * 64 + r) * DM + h * DKH + dt * 64 + cb;
  *(uint4*)&tile[r][cb]     = *(const uint4*)(src);
  *(uint4*)&tile[r][cb + 8] = *(const uint4*)(src + 8);
  __syncthreads();
  const int dr = tid >> 2, ncb = (tid & 3) << 4;
  u32 w[8];
#pragma unroll
  for (int u = 0; u < 8; u++)
    w[u] = (u32)tile[ncb + 2 * u][dr] | ((u32)tile[ncb + 2 * u + 1][dr] << 16);
  u16* dst = KT + ((size_t)((b * NH + h) * 256) + dt * 64 + dr) * NS + nt * 64 + ncb;
  *(uint4*)(dst)     = make_uint4(w[0], w[1], w[2], w[3]);
  *(uint4*)(dst + 8) = make_uint4(w[4], w[5], w[6], w[7]);
}

// ---------------- attention scores (MFMA) with decay, bf16 out [i][j] ----------------
__global__ __launch_bounds__(256) void attn_mfma(const u16* __restrict__ Q,
                                                 const u16* __restrict__ Kb,
                                                 u16* __restrict__ At) {
  __shared__ u16 sQ[64][264];
  __shared__ u16 sK[64][264];
  const int wg = blockIdx.x;          // (b*4+h)*64 + c
  const int c = wg & 63, h = (wg >> 6) & 3, b = wg >> 8;
  const int n0 = c << 6;
  const int tid = threadIdx.x;
  const int wave = tid >> 6, lane = tid & 63;
  const int quad = lane >> 4, col = lane & 15;
  {
    const int r = tid >> 2, cb = (tid & 3) << 6;
    const u16* qsrc = Q  + (size_t)(b * NS + n0 + r) * DM + h * DKH + cb;
    const u16* ksrc = Kb + (size_t)(b * NS + n0 + r) * DM + h * DKH + cb;
#pragma unroll
    for (int u = 0; u < 8; u++) {
      *(uint4*)&sQ[r][cb + u * 8] = *(const uint4*)(qsrc + u * 8);
      *(uint4*)&sK[r][cb + u * 8] = *(const uint4*)(ksrc + u * 8);
    }
  }
  __syncthreads();
  const int i0 = wave << 4;
  f32x4 acc[4] = {};
#pragma unroll
  for (int ks = 0; ks < 256; ks += 32) {
    bf16x8 a = *(const bf16x8*)&sQ[i0 + col][ks + quad * 8];
#pragma unroll
    for (int nt = 0; nt < 4; nt++) {
      bf16x8 bb = *(const bf16x8*)&sK[nt * 16 + col][ks + quad * 8];
      acc[nt] = mfma32(a, bb, acc[nt]);
    }
  }
  const float l2g = log2f(1.0f - exp2f(-5.0f - (float)h));
  u16* dst = At + ((size_t)wg << 12);
#pragma unroll
  for (int nt = 0; nt < 4; nt++) {
    int j = nt * 16 + col;
#pragma unroll
    for (int rr = 0; rr < 4; rr++) {
      int i = i0 + quad * 4 + rr;
      int rel = i - j;
      float v = (rel >= 0) ? acc[nt][rr] * exp2f((float)rel * l2g) : 0.0f;
      dst[i * 64 + j] = f2bf(v);
    }
  }
}

// ---------------- phase A: S recurrence -> bf16 checkpoints every 8 chunks ----
// 2048 single-wave wgs: wg = slice*8 + bh  (XCD-swizzle: all slices of a
// (b,h) group land on one XCD and share KT/VT in its L2).
// slice = ds(8) + 8*es(32): S-slice = 32 d x 16 e held in 2 MFMA accumulators.
// No LDS, no barriers: the S chain is the only serial dependency.
__global__ __launch_bounds__(64) void state_pass(const u16* __restrict__ KT,
                                                 const u16* __restrict__ VT,
                                                 u16* __restrict__ Sc) {
  const int wg = blockIdx.x;
  const int bh = wg & 7, slice = wg >> 3;
  const int ds = slice & 7, es = slice >> 3;
  const int b = bh >> 2, h = bh & 3;
  const int lane = threadIdx.x;
  const int quad = lane >> 4, col = lane & 15;
  const float gamma = 1.0f - exp2f(-5.0f - (float)h);
  const float l2g = log2f(gamma);
  const float gC = exp2f(64.0f * l2g);
  float ck[2][8];
#pragma unroll
  for (int ks = 0; ks < 2; ks++)
#pragma unroll
    for (int u = 0; u < 8; u++)
      ck[ks][u] = exp2f((float)(63 - (ks * 32 + quad * 8 + u)) * l2g);

  const u16* KTb = KT + (size_t)(bh * 256 + ds * 32) * NS;
  const u16* vrow = VT + (size_t)(h * DVH + es * 16 + col) * MROW + (size_t)b * NS;

  f32x4 S[2] = {};
  bf16x8 kf[2][4], vf[2][2];

  // prefetch chunk 0
#pragma unroll
  for (int mt = 0; mt < 2; mt++)
#pragma unroll
    for (int ks = 0; ks < 2; ks++)
      kf[0][mt * 2 + ks] = *(const bf16x8*)(KTb + (size_t)(mt * 16 + col) * NS + ks * 32 + quad * 8);
#pragma unroll
  for (int ks = 0; ks < 2; ks++)
    vf[0][ks] = *(const bf16x8*)(vrow + ks * 32 + quad * 8);

#pragma unroll 2
  for (int ch = 0; ch < NCH; ch++) {
    const int cur = ch & 1, nxt = cur ^ 1;
    if (ch + 1 < NCH) {
      const int n1 = (ch + 1) << 6;
#pragma unroll
      for (int mt = 0; mt < 2; mt++)
#pragma unroll
        for (int ks = 0; ks < 2; ks++)
          kf[nxt][mt * 2 + ks] = *(const bf16x8*)(KTb + (size_t)(mt * 16 + col) * NS + n1 + ks * 32 + quad * 8);
#pragma unroll
      for (int ks = 0; ks < 2; ks++)
        vf[nxt][ks] = *(const bf16x8*)(vrow + n1 + ks * 32 + quad * 8);
    }
#pragma unroll
    for (int mt = 0; mt < 2; mt++) S[mt] *= gC;
#pragma unroll
    for (int ks = 0; ks < 2; ks++) {
      bf16x8 ckv = scale8(vf[cur][ks], ck[ks]);
#pragma unroll
      for (int mt = 0; mt < 2; mt++)
        S[mt] = mfma32(kf[cur][mt * 2 + ks], ckv, S[mt]);
    }
    if ((ch & 7) == 7 && ch != NCH - 1) {
      const int sidx = ch >> 3;   // 0..6
      u16* sp = Sc + (size_t)((bh * 7 + sidx) * 512 + es * 16 + col) * 256 + ds * 32;
#pragma unroll
      for (int mt = 0; mt < 2; mt++) {
        ushort4 o;
        o.x = f2bf(S[mt][0]); o.y = f2bf(S[mt][1]);
        o.z = f2bf(S[mt][2]); o.w = f2bf(S[mt][3]);
        *(ushort4*)(sp + mt * 16 + quad * 4) = o;
      }
    }
  }
}

// ---------------- phase B: per-superchunk outputs, fully parallel -------------
// 1024 single-wave wgs: wg = grp + 64*es  (grp = bh*8+sc; same-(bh,sc) waves
// share an XCD's L2). Each wave owns a 32-wide e-slice for 8 chunks: loads the
// S checkpoint, recomputes S locally (MFMA accumulators), computes
// o = attn@V + cq*(q@S_prev). S->B-operand handoff is free: K=16 MFMA B-layout
// (4 k per quad) == MFMA C-layout (4 rows per quad) -> per-lane bf16 pack only.
// No LDS, no barriers anywhere.
__global__ __launch_bounds__(64, 1) void out_pass(const u16* __restrict__ Q,
                                                  const u16* __restrict__ KT,
                                                  const u16* __restrict__ At,
                                                  const u16* __restrict__ VT,
                                                  const u16* __restrict__ Sc,
                                                  u16* __restrict__ O) {
  const int wg = blockIdx.x;
  const int grp = wg & 63, es = wg >> 6;
  const int sc = grp & 7, bh = grp >> 3;
  const int b = bh >> 2, h = bh & 3;
  const int lane = threadIdx.x;
  const int quad = lane >> 4, col = lane & 15;
  const float gamma = 1.0f - exp2f(-5.0f - (float)h);
  const float l2g = log2f(gamma);
  const float gC = exp2f(64.0f * l2g);
  const float g16 = exp2f(16.0f * l2g);
  const float cq00 = exp2f((float)(quad * 4 + 1) * l2g);
  float ck[2][8];
#pragma unroll
  for (int ks = 0; ks < 2; ks++)
#pragma unroll
    for (int u = 0; u < 8; u++)
      ck[ks][u] = exp2f((float)(63 - (ks * 32 + quad * 8 + u)) * l2g);

  const u16* Qb  = Q + (size_t)(b * NS) * DM + h * DKH;
  const u16* KTb = KT + (size_t)(bh * 256) * NS;
  const u16* Atb = At + ((size_t)(bh * NCH) << 12);
  const u16* vrow0 = VT + (size_t)(h * DVH + es * 32 + col) * MROW + (size_t)b * NS;
  const u16* vrow1 = vrow0 + (size_t)16 * MROW;
  u16* Ob = O + (size_t)(b * NS) * VD + h * DVH + es * 32;

  f32x4 S[2][16];
  bf16x4 SB[2][16];
  if (sc) {
    const u16* sp0 = Sc + (size_t)((bh * 7 + sc - 1) * 512 + es * 32 + col) * 256;
    const u16* sp1 = sp0 + (size_t)16 * 256;
#pragma unroll
    for (int mt = 0; mt < 16; mt++) {
      ushort4 w0 = *(const ushort4*)(sp0 + mt * 16 + quad * 4);
      ushort4 w1 = *(const ushort4*)(sp1 + mt * 16 + quad * 4);
      SB[0][mt][0] = (short)w0.x; SB[0][mt][1] = (short)w0.y;
      SB[0][mt][2] = (short)w0.z; SB[0][mt][3] = (short)w0.w;
      SB[1][mt][0] = (short)w1.x; SB[1][mt][1] = (short)w1.y;
      SB[1][mt][2] = (short)w1.z; SB[1][mt][3] = (short)w1.w;
      S[0][mt] = f32x4{bf2f(w0.x), bf2f(w0.y), bf2f(w0.z), bf2f(w0.w)};
      S[1][mt] = f32x4{bf2f(w1.x), bf2f(w1.y), bf2f(w1.z), bf2f(w1.w)};
    }
  } else {
#pragma unroll
    for (int nt = 0; nt < 2; nt++)
#pragma unroll
      for (int mt = 0; mt < 16; mt++) { S[nt][mt] = f32x4{0.f, 0.f, 0.f, 0.f}; SB[nt][mt] = bf16x4{0, 0, 0, 0}; }
  }

  for (int c = 0; c < 8; c++) {
    const int ch = sc * 8 + c;
    const int n0 = ch << 6;
    f32x4 ai[4][2] = {}, ae[4][2] = {};
    bf16x8 vfr[2][2];
    // o_intra: attn @ V
#pragma unroll
    for (int ks = 0; ks < 2; ks++) {
      vfr[ks][0] = *(const bf16x8*)(vrow0 + n0 + ks * 32 + quad * 8);
      vfr[ks][1] = *(const bf16x8*)(vrow1 + n0 + ks * 32 + quad * 8);
#pragma unroll
      for (int mt = 0; mt < 4; mt++) {
        bf16x8 a = *(const bf16x8*)(Atb + ((size_t)ch << 12) + (mt * 16 + col) * 64 + ks * 32 + quad * 8);
        ai[mt][0] = mfma32(a, vfr[ks][0], ai[mt][0]);
        ai[mt][1] = mfma32(a, vfr[ks][1], ai[mt][1]);
      }
    }
    // o_inter: q @ S_prev (K=16 MFMAs, B = packed S accumulators)
    if (sc || c) {
#pragma unroll
      for (int kt = 0; kt < 16; kt++) {
#pragma unroll
        for (int mt = 0; mt < 4; mt++) {
          ushort4 qa = *(const ushort4*)(Qb + (size_t)(n0 + mt * 16 + col) * DM + kt * 16 + quad * 4);
          bf16x4 a; a[0] = (short)qa.x; a[1] = (short)qa.y; a[2] = (short)qa.z; a[3] = (short)qa.w;
          ae[mt][0] = mfma16(a, SB[0][kt], ae[mt][0]);
          ae[mt][1] = mfma16(a, SB[1][kt], ae[mt][1]);
        }
      }
    }
    // write o
    float cqr = cq00;
#pragma unroll
    for (int mt = 0; mt < 4; mt++) {
      float cq = cqr;
#pragma unroll
      for (int r = 0; r < 4; r++) {
        u16* dst = Ob + (size_t)(n0 + mt * 16 + quad * 4 + r) * VD;
        dst[col]      = f2bf(ai[mt][0][r] + cq * ae[mt][0][r]);
        dst[16 + col] = f2bf(ai[mt][1][r] + cq * ae[mt][1][r]);
        cq *= gamma;
      }
      cqr *= g16;
    }
    // local S update
    if (c < 7) {
#pragma unroll
      for (int nt = 0; nt < 2; nt++)
#pragma unroll
        for (int mt = 0; mt < 16; mt++) S[nt][mt] *= gC;
#pragma unroll
      for (int ks = 0; ks < 2; ks++) {
        bf16x8 ckv0 = scale8(vfr[ks][0], ck[ks]);
        bf16x8 ckv1 = scale8(vfr[ks][1], ck[ks]);
#pragma unroll
        for (int mt = 0; mt < 16; mt++) {
          bf16x8 a = *(const bf16x8*)(KTb + (size_t)(mt * 16 + col) * NS + n0 + ks * 32 + quad * 8);
          S[0][mt] = mfma32(a, ckv0, S[0][mt]);
          S[1][mt] = mfma32(a, ckv1, S[1][mt]);
        }
      }
#pragma unroll
      for (int nt = 0; nt < 2; nt++)
#pragma unroll
        for (int mt = 0; mt < 16; mt++) SB[nt][mt] = pack4(S[nt][mt]);
    }
  }
}

// ---------------- groupnorm (rms over 512 per head) * silu(gate) ----------------
__global__ __launch_bounds__(256) void norm_gate_kernel(const u16* __restrict__ O,
                                                        const u16* __restrict__ G,
                                                        const float* __restrict__ gnw,
                                                        u16* __restrict__ OG) {
  const int bn = blockIdx.x;            // 0..B*N-1
  const int wave = threadIdx.x >> 6;    // head
  const int lane = threadIdx.x & 63;
  const size_t base = (size_t)bn * VD + (size_t)wave * DVH;
  float vals[8];
  float ss = 0.f;
#pragma unroll
  for (int k = 0; k < 8; k++) {
    float v = bf2f(O[base + lane + 64 * k]);
    vals[k] = v;
    ss += v * v;
  }
#pragma unroll
  for (int off = 32; off > 0; off >>= 1) ss += __shfl_xor(ss, off, 64);
  const float r = rsqrtf(ss * (1.0f / 512.0f) + 1e-5f);
#pragma unroll
  for (int k = 0; k < 8; k++) {
    int e = lane + 64 * k;
    float g = bf2f(G[base + e]);
    float sig = 1.0f / (1.0f + expf(-g));
    OG[base + e] = f2bf(vals[k] * r * gnw[e] * g * sig);
  }
}

// ---------------- launch ----------------
extern "C" void kernel_launch(void* const* d_in, const int* in_sizes, int n_in,
                              void* d_out, int out_size, void* d_ws, size_t ws_size,
                              hipStream_t stream) {
  const float* x   = (const float*)d_in[0];
  const float* Wq  = (const float*)d_in[1];
  const float* Wk  = (const float*)d_in[2];
  const float* Wv  = (const float*)d_in[3];
  const float* Wg  = (const float*)d_in[4];
  const float* Wo  = (const float*)d_in[5];
  const float* gnw = (const float*)d_in[6];

  char* ws = (char*)d_ws;
  u16*   xb  = (u16*)(ws);                          // 16 MB (dead after projections)
  u16*   Sc  = (u16*)(ws);                          // 14.7 MB overlay on xb (phase A/B)
  u16*   Qb  = (u16*)(ws + (16u  << 20));           // 16 MB
  u16*   Kb  = (u16*)(ws + (32u  << 20));           // 16 MB
  u16*   VT  = (u16*)(ws + (48u  << 20));           // 32 MB (V^T: [h*512+e][b*4096+n])
  u16*   Gb  = (u16*)(ws + (80u  << 20));           // 32 MB
  u16*   At  = (u16*)(ws + (112u << 20));           // 4 MB
  u16*   KTg = (u16*)(ws + (116u << 20));           // 16 MB (b,h,d,n)
  u16*   Wqt = (u16*)(ws + (132u << 20));           // 2 MB
  u16*   Wkt = (u16*)(ws + (134u << 20));           // 2 MB
  u16*   Wvt = (u16*)(ws + (136u << 20));           // 4 MB
  u16*   Wgt = (u16*)(ws + (140u << 20));           // 4 MB
  u16*   Wot = (u16*)(ws + (144u << 20));           // 4 MB
  u16*   Ob  = (u16*)(ws + (148u << 20));           // 32 MB row-major o  -> 180 MB
  u16*   OG  = (u16*)(ws);                          // 32 MB overlay (Sc+Qb dead by then)

  dim3 blk(256);
  const int M = MROW;   // 8192

  cvt_bf16<<<8192, blk, 0, stream>>>(x, xb);
  transpose_bf16<<<dim3(16, 16), blk, 0, stream>>>(Wq, Wqt, DM, DM);
  transpose_bf16<<<dim3(16, 16), blk, 0, stream>>>(Wk, Wkt, DM, DM);
  transpose_bf16<<<dim3(32, 16), blk, 0, stream>>>(Wv, Wvt, DM, VD);
  transpose_bf16<<<dim3(32, 16), blk, 0, stream>>>(Wg, Wgt, DM, VD);
  transpose_bf16<<<dim3(16, 32), blk, 0, stream>>>(Wo, Wot, VD, DM);

  gemm_mfma<1><<<dim3(8, 64),  blk, 0, stream>>>(xb, Wqt, Qb, M, DM, DM);
  gemm_mfma<1><<<dim3(8, 64),  blk, 0, stream>>>(xb, Wkt, Kb, M, DM, DM);
  gemm_mfma<2><<<dim3(16, 64), blk, 0, stream>>>(xb, Wvt, VT, M, VD, DM);   // -> V^T
  gemm_mfma<1><<<dim3(16, 64), blk, 0, stream>>>(xb, Wgt, Gb, M, VD, DM);

  rope_kernel<<<16384, blk, 0, stream>>>(Qb, Kb);
  transpose_k<<<2048, blk, 0, stream>>>(Kb, KTg);
  attn_mfma<<<512, blk, 0, stream>>>(Qb, Kb, At);

  state_pass<<<2048, dim3(64), 0, stream>>>(KTg, VT, Sc);
  out_pass<<<1024, dim3(64), 0, stream>>>(Qb, KTg, At, VT, Sc, Ob);

  norm_gate_kernel<<<M, blk, 0, stream>>>(Ob, Gb, gnw, OG);
  gemm_mfma<0><<<dim3(8, 64), blk, 0, stream>>>(OG, Wot, (float*)d_out, M, DM, VD);
}

// Round 6
// 645.465 us; speedup vs baseline: 1.0362x; 1.0362x over previous
//
#include <hip/hip_runtime.h>

// ---------------- problem constants ----------------
#define NS   4096      // sequence length
#define NBAT 2         // batch
#define NH   4         // heads
#define DKH  256       // head qk dim
#define DVH  512       // head v dim
#define DM   1024      // d_model
#define VD   2048      // value dim
#define CH   64        // chunk
#define NCH  64        // num chunks
#define MROW (NBAT * NS)   // 8192

typedef unsigned short u16;
typedef unsigned int   u32;

using bf16x8 = __attribute__((ext_vector_type(8))) short;
using f32x4  = __attribute__((ext_vector_type(4))) float;

__device__ __forceinline__ float bf2f(u16 a) {
  return __uint_as_float(((u32)a) << 16);
}
__device__ __forceinline__ u16 f2bf(float f) {
  u32 u = __float_as_uint(f);
  u32 r = (u + 0x7fffu + ((u >> 16) & 1u)) >> 16;   // RNE
  return (u16)r;
}
__device__ __forceinline__ void unpack2(u32 v, float& lo, float& hi) {
  lo = __uint_as_float(v << 16);
  hi = __uint_as_float(v & 0xffff0000u);
}
__device__ __forceinline__ void unpack8(uint4 v, float* f) {
  unpack2(v.x, f[0], f[1]); unpack2(v.y, f[2], f[3]);
  unpack2(v.z, f[4], f[5]); unpack2(v.w, f[6], f[7]);
}

__device__ __forceinline__ void gl_lds16(const u16* g, u16* l) {
  __builtin_amdgcn_global_load_lds(
      (const __attribute__((address_space(1))) void*)g,
      (__attribute__((address_space(3))) void*)l,
      16, 0, 0);
}

__device__ __forceinline__ f32x4 mfma32(bf16x8 a, bf16x8 b, f32x4 c) {
  return __builtin_amdgcn_mfma_f32_16x16x32_bf16(a, b, c, 0, 0, 0);
}

// scale a B-fragment's 8 bf16 by per-element k factors
__device__ __forceinline__ bf16x8 scale8(bf16x8 v, const float* ckv) {
  u32* w = (u32*)&v;
  bf16x8 out;
  u32* ow = (u32*)&out;
#pragma unroll
  for (int p = 0; p < 4; p++) {
    float lo, hi; unpack2(w[p], lo, hi);
    ow[p] = (u32)f2bf(lo * ckv[2 * p]) | ((u32)f2bf(hi * ckv[2 * p + 1]) << 16);
  }
  return out;
}

// ---------------- f32 -> bf16 convert ----------------
__global__ __launch_bounds__(256) void cvt_bf16(const float* __restrict__ X,
                                                u16* __restrict__ Y) {
  size_t t = (size_t)blockIdx.x * 256 + threadIdx.x;
  float4 v = *(const float4*)(X + t * 4);
  ushort4 o;
  o.x = f2bf(v.x); o.y = f2bf(v.y); o.z = f2bf(v.z); o.w = f2bf(v.w);
  *(ushort4*)(Y + t * 4) = o;
}

// ---------------- f32 KxN -> bf16 NxK transpose-convert ----------------
__global__ __launch_bounds__(256) void transpose_bf16(const float* __restrict__ W,
                                                      u16* __restrict__ Wt,
                                                      int K, int N) {
  __shared__ float tile[64][65];
  const int n0 = blockIdx.x * 64, k0 = blockIdx.y * 64;
  const int t = threadIdx.x;
  const int r = t >> 4, c = (t & 15) << 2;
#pragma unroll
  for (int it = 0; it < 4; it++) {
    float4 v = *(const float4*)(W + (size_t)(k0 + r + it * 16) * N + n0 + c);
    tile[r + it * 16][c + 0] = v.x; tile[r + it * 16][c + 1] = v.y;
    tile[r + it * 16][c + 2] = v.z; tile[r + it * 16][c + 3] = v.w;
  }
  __syncthreads();
#pragma unroll
  for (int it = 0; it < 4; it++) {
    const int nr = r + it * 16;
    ushort4 o;
    o.x = f2bf(tile[c + 0][nr]); o.y = f2bf(tile[c + 1][nr]);
    o.z = f2bf(tile[c + 2][nr]); o.w = f2bf(tile[c + 3][nr]);
    *(ushort4*)(Wt + (size_t)(n0 + nr) * K + k0 + c) = o;
  }
}

// ---------------- MFMA GEMM: C = A @ Bt^T ----------------
// OMODE: 0 = f32 row-major, 1 = bf16 row-major, 2 = bf16 transposed (ldC = M)
template<int OMODE>
__global__ __launch_bounds__(256) void gemm_mfma(const u16* __restrict__ A,
                                                 const u16* __restrict__ Bt,
                                                 void* __restrict__ C,
                                                 int M, int N, int K) {
  __shared__ u16 sA[128 * 64];
  __shared__ u16 sB[128 * 64];
  const int tid = threadIdx.x;
  const int wave = tid >> 6, lane = tid & 63;
  const int wm = (wave >> 1) << 6;
  const int wn = (wave & 1) << 6;
  const int row0 = blockIdx.y << 7, col0 = blockIdx.x << 7;

  const int srow = tid >> 3;
  const int sk   = (tid & 7) << 3;

  const u16* aRow = A + (size_t)(row0 + srow) * K + sk;
  const u16* bRow = Bt + (size_t)(col0 + srow) * K + sk;
  u16* sAp = sA + tid * 8;
  u16* sBp = sB + tid * 8;

  f32x4 acc[4][4] = {};

  const int fm = lane & 15;
  const int fk = (lane >> 4) << 3;
  const u16* sAf = sA + (wm + fm) * 64 + fk;
  const u16* sBf = sB + (wn + fm) * 64 + fk;

  for (int k0 = 0; k0 < K; k0 += 64) {
#pragma unroll
    for (int it = 0; it < 4; it++) {
      gl_lds16(aRow + (size_t)(it * 32) * K + k0, sAp + it * 2048);
      gl_lds16(bRow + (size_t)(it * 32) * K + k0, sBp + it * 2048);
    }
    __syncthreads();
#pragma unroll
    for (int kk = 0; kk < 64; kk += 32) {
      bf16x8 af[4], bfr[4];
#pragma unroll
      for (int mt = 0; mt < 4; mt++) af[mt] = *(const bf16x8*)(sAf + mt * 1024 + kk);
#pragma unroll
      for (int nt = 0; nt < 4; nt++) bfr[nt] = *(const bf16x8*)(sBf + nt * 1024 + kk);
#pragma unroll
      for (int mt = 0; mt < 4; mt++)
#pragma unroll
        for (int nt = 0; nt < 4; nt++)
          acc[mt][nt] = mfma32(af[mt], bfr[nt], acc[mt][nt]);
    }
    __syncthreads();
  }

  const int er = lane >> 4;
  const int ec = lane & 15;
#pragma unroll
  for (int mt = 0; mt < 4; mt++) {
#pragma unroll
    for (int nt = 0; nt < 4; nt++) {
      if constexpr (OMODE == 2) {
        ushort4 o;
        o.x = f2bf(acc[mt][nt][0]); o.y = f2bf(acc[mt][nt][1]);
        o.z = f2bf(acc[mt][nt][2]); o.w = f2bf(acc[mt][nt][3]);
        u16* dst = (u16*)C + (size_t)(col0 + wn + nt * 16 + ec) * M +
                   row0 + wm + mt * 16 + er * 4;
        *(ushort4*)dst = o;
      } else {
#pragma unroll
        for (int r = 0; r < 4; r++) {
          const size_t row = (size_t)row0 + wm + mt * 16 + er * 4 + r;
          const size_t col = (size_t)col0 + wn + nt * 16 + ec;
          if constexpr (OMODE == 1) ((u16*)C)[row * N + col] = f2bf(acc[mt][nt][r]);
          else                      ((float*)C)[row * N + col] = acc[mt][nt][r];
        }
      }
    }
  }
}

// ---------------- RoPE (in-place on bf16 Q,K) + q scale ----------------
__global__ __launch_bounds__(256) void rope_kernel(u16* __restrict__ Q, u16* __restrict__ K) {
  size_t t = (size_t)blockIdx.x * 256 + threadIdx.x;   // B*N*NH*128 total
  int j = (int)(t & 127);
  int h = (int)((t >> 7) & 3);
  size_t bn = t >> 9;
  int n = (int)(bn & (NS - 1));
  float ang = (float)n * exp2f(-(float)j * (13.2877123795494f / 128.0f));
  float s, c;
  sincosf(ang, &s, &c);
  size_t base = bn * DM + (size_t)h * DKH + j;
  const float sc = 0.0625f;   // HEAD_QK^-0.5
  float q1 = bf2f(Q[base]), q2 = bf2f(Q[base + 128]);
  Q[base]       = f2bf((q1 * c - q2 * s) * sc);
  Q[base + 128] = f2bf((q2 * c + q1 * s) * sc);
  float k1 = bf2f(K[base]), k2 = bf2f(K[base + 128]);
  K[base]       = f2bf(k1 * c - k2 * s);
  K[base + 128] = f2bf(k2 * c + k1 * s);
}

// ---------------- K -> K^T (per head): KT[b,h,d,n] ----------------
__global__ __launch_bounds__(256) void transpose_k(const u16* __restrict__ Kb,
                                                   u16* __restrict__ KT) {
  __shared__ u16 tile[64][68];
  const int wg = blockIdx.x;
  const int dt = wg & 3, nt = (wg >> 2) & 63, h = (wg >> 8) & 3, b = wg >> 10;
  const int tid = threadIdx.x;
  const int r = tid >> 2, cb = (tid & 3) << 4;
  const u16* src = Kb + (size_t)(b * NS + nt * 64 + r) * DM + h * DKH + dt * 64 + cb;
  *(uint4*)&tile[r][cb]     = *(const uint4*)(src);
  *(uint4*)&tile[r][cb + 8] = *(const uint4*)(src + 8);
  __syncthreads();
  const int dr = tid >> 2, ncb = (tid & 3) << 4;
  u32 w[8];
#pragma unroll
  for (int u = 0; u < 8; u++)
    w[u] = (u32)tile[ncb + 2 * u][dr] | ((u32)tile[ncb + 2 * u + 1][dr] << 16);
  u16* dst = KT + ((size_t)((b * NH + h) * 256) + dt * 64 + dr) * NS + nt * 64 + ncb;
  *(uint4*)(dst)     = make_uint4(w[0], w[1], w[2], w[3]);
  *(uint4*)(dst + 8) = make_uint4(w[4], w[5], w[6], w[7]);
}

// ---------------- attention scores (MFMA) with decay, bf16 out [i][j] ----------------
__global__ __launch_bounds__(256) void attn_mfma(const u16* __restrict__ Q,
                                                 const u16* __restrict__ Kb,
                                                 u16* __restrict__ At) {
  __shared__ u16 sQ[64][264];
  __shared__ u16 sK[64][264];
  const int wg = blockIdx.x;          // (b*4+h)*64 + c
  const int c = wg & 63, h = (wg >> 6) & 3, b = wg >> 8;
  const int n0 = c << 6;
  const int tid = threadIdx.x;
  const int wave = tid >> 6, lane = tid & 63;
  const int quad = lane >> 4, col = lane & 15;
  {
    const int r = tid >> 2, cb = (tid & 3) << 6;
    const u16* qsrc = Q  + (size_t)(b * NS + n0 + r) * DM + h * DKH + cb;
    const u16* ksrc = Kb + (size_t)(b * NS + n0 + r) * DM + h * DKH + cb;
#pragma unroll
    for (int u = 0; u < 8; u++) {
      *(uint4*)&sQ[r][cb + u * 8] = *(const uint4*)(qsrc + u * 8);
      *(uint4*)&sK[r][cb + u * 8] = *(const uint4*)(ksrc + u * 8);
    }
  }
  __syncthreads();
  const int i0 = wave << 4;
  f32x4 acc[4] = {};
#pragma unroll
  for (int ks = 0; ks < 256; ks += 32) {
    bf16x8 a = *(const bf16x8*)&sQ[i0 + col][ks + quad * 8];
#pragma unroll
    for (int nt = 0; nt < 4; nt++) {
      bf16x8 bb = *(const bf16x8*)&sK[nt * 16 + col][ks + quad * 8];
      acc[nt] = mfma32(a, bb, acc[nt]);
    }
  }
  const float l2g = log2f(1.0f - exp2f(-5.0f - (float)h));
  u16* dst = At + ((size_t)wg << 12);
#pragma unroll
  for (int nt = 0; nt < 4; nt++) {
    int j = nt * 16 + col;
#pragma unroll
    for (int rr = 0; rr < 4; rr++) {
      int i = i0 + quad * 4 + rr;
      int rel = i - j;
      float v = (rel >= 0) ? acc[nt][rr] * exp2f((float)rel * l2g) : 0.0f;
      dst[i * 64 + j] = f2bf(v);
    }
  }
}

// ---------------- phase A: S recurrence -> bf16 checkpoints every 8 chunks ----
// 2048 single-wave wgs: wg = slice*8 + bh. slice = ds(8) + 8*es(32):
// S-slice = 32 d x 16 e in 2 MFMA accumulators. No LDS, no barriers.
// Only 56 chunks needed (last checkpoint is after chunk 55).
__global__ __launch_bounds__(64) void state_pass(const u16* __restrict__ KT,
                                                 const u16* __restrict__ VT,
                                                 u16* __restrict__ Sc) {
  const int wg = blockIdx.x;
  const int bh = wg & 7, slice = wg >> 3;
  const int ds = slice & 7, es = slice >> 3;
  const int b = bh >> 2, h = bh & 3;
  const int lane = threadIdx.x;
  const int quad = lane >> 4, col = lane & 15;
  const float gamma = 1.0f - exp2f(-5.0f - (float)h);
  const float l2g = log2f(gamma);
  const float gC = exp2f(64.0f * l2g);
  float ck[2][8];
#pragma unroll
  for (int ks = 0; ks < 2; ks++)
#pragma unroll
    for (int u = 0; u < 8; u++)
      ck[ks][u] = exp2f((float)(63 - (ks * 32 + quad * 8 + u)) * l2g);

  const u16* KTb = KT + (size_t)(bh * 256 + ds * 32) * NS;
  const u16* vrow = VT + (size_t)(h * DVH + es * 16 + col) * MROW + (size_t)b * NS;

  f32x4 S[2] = {};
  bf16x8 kf[2][4], vf[2][2];

  // prefetch chunk 0
#pragma unroll
  for (int mt = 0; mt < 2; mt++)
#pragma unroll
    for (int ks = 0; ks < 2; ks++)
      kf[0][mt * 2 + ks] = *(const bf16x8*)(KTb + (size_t)(mt * 16 + col) * NS + ks * 32 + quad * 8);
#pragma unroll
  for (int ks = 0; ks < 2; ks++)
    vf[0][ks] = *(const bf16x8*)(vrow + ks * 32 + quad * 8);

#pragma unroll 2
  for (int ch = 0; ch < 56; ch++) {
    const int cur = ch & 1, nxt = cur ^ 1;
    if (ch + 1 < 56) {
      const int n1 = (ch + 1) << 6;
#pragma unroll
      for (int mt = 0; mt < 2; mt++)
#pragma unroll
        for (int ks = 0; ks < 2; ks++)
          kf[nxt][mt * 2 + ks] = *(const bf16x8*)(KTb + (size_t)(mt * 16 + col) * NS + n1 + ks * 32 + quad * 8);
#pragma unroll
      for (int ks = 0; ks < 2; ks++)
        vf[nxt][ks] = *(const bf16x8*)(vrow + n1 + ks * 32 + quad * 8);
    }
#pragma unroll
    for (int mt = 0; mt < 2; mt++) S[mt] *= gC;
#pragma unroll
    for (int ks = 0; ks < 2; ks++) {
      bf16x8 ckv = scale8(vf[cur][ks], ck[ks]);
#pragma unroll
      for (int mt = 0; mt < 2; mt++)
        S[mt] = mfma32(kf[cur][mt * 2 + ks], ckv, S[mt]);
    }
    if ((ch & 7) == 7) {
      const int sidx = ch >> 3;   // 0..6
      u16* sp = Sc + (size_t)((bh * 7 + sidx) * 512 + es * 16 + col) * 256 + ds * 32;
#pragma unroll
      for (int mt = 0; mt < 2; mt++) {
        ushort4 o;
        o.x = f2bf(S[mt][0]); o.y = f2bf(S[mt][1]);
        o.z = f2bf(S[mt][2]); o.w = f2bf(S[mt][3]);
        *(ushort4*)(sp + mt * 16 + quad * 4) = o;
      }
    }
  }
}

// ---------------- phase B: per-superchunk outputs, fully parallel -------------
// 512 wgs x 256 thr (4 waves): wg = ev*64 + bh*8 + sc  (XCD swizzle: same
// (bh,sc) sharers land on one XCD). Each WAVE owns a 16-wide e-slice
// (e0 = (ev*4+wv)*16): loads the S checkpoint, then for 8 chunks computes
// o = attn@V + cq*(q@S_prev) and recomputes S locally (16 f32x4 accumulators).
// S^T handoff to the o_inter B-operand goes through a PER-WAVE private LDS
// region -> zero barriers anywhere (same-wave DS ops are in-order).
// Waves of a wg read identical Q/KT/At fragments -> L1-hot.
__global__ __launch_bounds__(256) void out_pass(const u16* __restrict__ Q,
                                                const u16* __restrict__ KT,
                                                const u16* __restrict__ At,
                                                const u16* __restrict__ VT,
                                                const u16* __restrict__ Sc,
                                                u16* __restrict__ O) {
  __shared__ u16 sSb[4][16][264];   // per-wave S^T bf16 [e][d]
  const int wg = blockIdx.x;
  const int ev = wg >> 6, grp = wg & 63;
  const int sc = grp & 7, bh = grp >> 3;
  const int b = bh >> 2, h = bh & 3;
  const int tid = threadIdx.x;
  const int wv = tid >> 6, lane = tid & 63;
  const int quad = lane >> 4, col = lane & 15;
  const int e0 = (ev * 4 + wv) << 4;     // this wave's e base (0..496)
  u16 (*mySb)[264] = sSb[wv];

  const float gamma = 1.0f - exp2f(-5.0f - (float)h);
  const float l2g = log2f(gamma);
  const float gC = exp2f(64.0f * l2g);
  const float g16 = exp2f(16.0f * l2g);
  const float cq00 = exp2f((float)(quad * 4 + 1) * l2g);
  float ck[2][8];
#pragma unroll
  for (int ks = 0; ks < 2; ks++)
#pragma unroll
    for (int u = 0; u < 8; u++)
      ck[ks][u] = exp2f((float)(63 - (ks * 32 + quad * 8 + u)) * l2g);

  const u16* Qbh  = Q + (size_t)(b * NS) * DM + h * DKH;
  const u16* KTbh = KT + (size_t)(bh * 256) * NS;
  const u16* Atbh = At + ((size_t)(bh * NCH) << 12);
  const u16* vrow = VT + (size_t)(h * DVH + e0 + col) * MROW + (size_t)b * NS;
  u16* Obh = O + (size_t)(b * NS) * VD + h * DVH + e0;

  // ---- init S (f32 accumulators, C-layout [d][e]) + S^T bf16 in LDS ----
  f32x4 S[16];
  if (sc) {
    const u16* sp = Sc + (size_t)((bh * 7 + sc - 1) * 512 + e0 + col) * 256;
#pragma unroll
    for (int mt = 0; mt < 16; mt++) {
      ushort4 w = *(const ushort4*)(sp + mt * 16 + quad * 4);
      *(ushort4*)&mySb[col][mt * 16 + quad * 4] = w;
      S[mt] = f32x4{bf2f(w.x), bf2f(w.y), bf2f(w.z), bf2f(w.w)};
    }
  } else {
    const ushort4 z = {0, 0, 0, 0};
#pragma unroll
    for (int mt = 0; mt < 16; mt++) {
      *(ushort4*)&mySb[col][mt * 16 + quad * 4] = z;
      S[mt] = f32x4{0.f, 0.f, 0.f, 0.f};
    }
  }

  for (int c = 0; c < 8; c++) {
    const int ch = sc * 8 + c;
    const int n0 = ch << 6;
    // V fragments for this wave's e-slice (used by both intra and S-update)
    bf16x8 vfr[2];
    vfr[0] = *(const bf16x8*)(vrow + n0 + quad * 8);
    vfr[1] = *(const bf16x8*)(vrow + n0 + 32 + quad * 8);
    // ---- o_intra: attn @ V ----
    f32x4 ai[4] = {};
#pragma unroll
    for (int ks = 0; ks < 2; ks++)
#pragma unroll
      for (int mt = 0; mt < 4; mt++) {
        bf16x8 a = *(const bf16x8*)(Atbh + ((size_t)ch << 12) + (mt * 16 + col) * 64 + ks * 32 + quad * 8);
        ai[mt] = mfma32(a, vfr[ks], ai[mt]);
      }
    // ---- o_inter: q @ S_prev (B-frags from per-wave LDS S^T) ----
    f32x4 ae[4] = {};
    if (ch) {
#pragma unroll
      for (int ks = 0; ks < 8; ks++) {
        bf16x8 bb = *(const bf16x8*)&mySb[col][ks * 32 + quad * 8];
#pragma unroll
        for (int mt = 0; mt < 4; mt++) {
          bf16x8 a = *(const bf16x8*)(Qbh + (size_t)(n0 + mt * 16 + col) * DM + ks * 32 + quad * 8);
          ae[mt] = mfma32(a, bb, ae[mt]);
        }
      }
    }
    // ---- write o ----
    float cqr = cq00;
#pragma unroll
    for (int mt = 0; mt < 4; mt++) {
      float cq = cqr;
#pragma unroll
      for (int r = 0; r < 4; r++) {
        u16* dst = Obh + (size_t)(n0 + mt * 16 + quad * 4 + r) * VD + col;
        *dst = f2bf(ai[mt][r] + cq * ae[mt][r]);
        cq *= gamma;
      }
      cqr *= g16;
    }
    // ---- local S update + LDS write-through ----
    if (c < 7) {
#pragma unroll
      for (int mt = 0; mt < 16; mt++) S[mt] *= gC;
#pragma unroll
      for (int ks = 0; ks < 2; ks++) {
        bf16x8 ckv = scale8(vfr[ks], ck[ks]);
#pragma unroll
        for (int mt = 0; mt < 16; mt++) {
          bf16x8 a = *(const bf16x8*)(KTbh + (size_t)(mt * 16 + col) * NS + n0 + ks * 32 + quad * 8);
          S[mt] = mfma32(a, ckv, S[mt]);
        }
      }
#pragma unroll
      for (int mt = 0; mt < 16; mt++) {
        ushort4 o4;
        o4.x = f2bf(S[mt][0]); o4.y = f2bf(S[mt][1]);
        o4.z = f2bf(S[mt][2]); o4.w = f2bf(S[mt][3]);
        *(ushort4*)&mySb[col][mt * 16 + quad * 4] = o4;
      }
    }
  }
}

// ---------------- groupnorm (rms over 512 per head) * silu(gate) ----------------
__global__ __launch_bounds__(256) void norm_gate_kernel(const u16* __restrict__ O,
                                                        const u16* __restrict__ G,
                                                        const float* __restrict__ gnw,
                                                        u16* __restrict__ OG) {
  const int bn = blockIdx.x;            // 0..B*N-1
  const int wave = threadIdx.x >> 6;    // head
  const int lane = threadIdx.x & 63;
  const size_t base = (size_t)bn * VD + (size_t)wave * DVH;
  float vals[8];
  float ss = 0.f;
#pragma unroll
  for (int k = 0; k < 8; k++) {
    float v = bf2f(O[base + lane + 64 * k]);
    vals[k] = v;
    ss += v * v;
  }
#pragma unroll
  for (int off = 32; off > 0; off >>= 1) ss += __shfl_xor(ss, off, 64);
  const float r = rsqrtf(ss * (1.0f / 512.0f) + 1e-5f);
#pragma unroll
  for (int k = 0; k < 8; k++) {
    int e = lane + 64 * k;
    float g = bf2f(G[base + e]);
    float sig = 1.0f / (1.0f + expf(-g));
    OG[base + e] = f2bf(vals[k] * r * gnw[e] * g * sig);
  }
}

// ---------------- launch ----------------
extern "C" void kernel_launch(void* const* d_in, const int* in_sizes, int n_in,
                              void* d_out, int out_size, void* d_ws, size_t ws_size,
                              hipStream_t stream) {
  const float* x   = (const float*)d_in[0];
  const float* Wq  = (const float*)d_in[1];
  const float* Wk  = (const float*)d_in[2];
  const float* Wv  = (const float*)d_in[3];
  const float* Wg  = (const float*)d_in[4];
  const float* Wo  = (const float*)d_in[5];
  const float* gnw = (const float*)d_in[6];

  char* ws = (char*)d_ws;
  u16*   xb  = (u16*)(ws);                          // 16 MB (dead after projections)
  u16*   Sc  = (u16*)(ws);                          // 14.7 MB overlay on xb (phase A/B)
  u16*   Qb  = (u16*)(ws + (16u  << 20));           // 16 MB
  u16*   Kb  = (u16*)(ws + (32u  << 20));           // 16 MB
  u16*   VT  = (u16*)(ws + (48u  << 20));           // 32 MB (V^T: [h*512+e][b*4096+n])
  u16*   Gb  = (u16*)(ws + (80u  << 20));           // 32 MB
  u16*   At  = (u16*)(ws + (112u << 20));           // 4 MB
  u16*   KTg = (u16*)(ws + (116u << 20));           // 16 MB (b,h,d,n)
  u16*   Wqt = (u16*)(ws + (132u << 20));           // 2 MB
  u16*   Wkt = (u16*)(ws + (134u << 20));           // 2 MB
  u16*   Wvt = (u16*)(ws + (136u << 20));           // 4 MB
  u16*   Wgt = (u16*)(ws + (140u << 20));           // 4 MB
  u16*   Wot = (u16*)(ws + (144u << 20));           // 4 MB
  u16*   Ob  = (u16*)(ws + (148u << 20));           // 32 MB row-major o  -> 180 MB
  u16*   OG  = (u16*)(ws);                          // 32 MB overlay (Sc+Qb dead by then)

  dim3 blk(256);
  const int M = MROW;   // 8192

  cvt_bf16<<<8192, blk, 0, stream>>>(x, xb);
  transpose_bf16<<<dim3(16, 16), blk, 0, stream>>>(Wq, Wqt, DM, DM);
  transpose_bf16<<<dim3(16, 16), blk, 0, stream>>>(Wk, Wkt, DM, DM);
  transpose_bf16<<<dim3(32, 16), blk, 0, stream>>>(Wv, Wvt, DM, VD);
  transpose_bf16<<<dim3(32, 16), blk, 0, stream>>>(Wg, Wgt, DM, VD);
  transpose_bf16<<<dim3(16, 32), blk, 0, stream>>>(Wo, Wot, VD, DM);

  gemm_mfma<1><<<dim3(8, 64),  blk, 0, stream>>>(xb, Wqt, Qb, M, DM, DM);
  gemm_mfma<1><<<dim3(8, 64),  blk, 0, stream>>>(xb, Wkt, Kb, M, DM, DM);
  gemm_mfma<2><<<dim3(16, 64), blk, 0, stream>>>(xb, Wvt, VT, M, VD, DM);   // -> V^T
  gemm_mfma<1><<<dim3(16, 64), blk, 0, stream>>>(xb, Wgt, Gb, M, VD, DM);

  rope_kernel<<<16384, blk, 0, stream>>>(Qb, Kb);
  transpose_k<<<2048, blk, 0, stream>>>(Kb, KTg);
  attn_mfma<<<512, blk, 0, stream>>>(Qb, Kb, At);

  state_pass<<<2048, dim3(64), 0, stream>>>(KTg, VT, Sc);
  out_pass<<<512, blk, 0, stream>>>(Qb, KTg, At, VT, Sc, Ob);

  norm_gate_kernel<<<M, blk, 0, stream>>>(Ob, Gb, gnw, OG);
  gemm_mfma<0><<<dim3(8, 64), blk, 0, stream>>>(OG, Wot, (float*)d_out, M, DM, VD);
}